// Round 3
// baseline (141.954 us; speedup 1.0000x reference)
//
#include <hip/hip_runtime.h>

#define NB   8192
#define NT   2048
#define OBS  30
#define LCH  64               // chunk length (>= OBS so state == last-30 outputs)
#define CCH  32               // chunks per row (LCH*CCH == NT)
#define NCHAIN (NB*CCH)       // 262144 independent chains
#define NBLKA  (NCHAIN/256)   // 1024 work blocks for pass A

// C[t][k] = homogeneous output at local step t starting from unit state e_k.
// Rows 34..63 are exactly A^LCH (state_final[i] = out[34+i]).
__device__ float g_C[LCH * 32];

// One recurrence step on a 32-slot register ring.
// Invariant: before step t, state s_t[i] lives at r[(t+i)&31], i=0..29.
// j == t mod 32 must be a compile-time constant (callers fully unroll).
__device__ __forceinline__ float step_ring(float (&r)[32], const float (&wx)[OBS],
                                           int j, float uwf) {
  float a0 = wx[0] * r[(j + 0) & 31];
  float a1 = wx[1] * r[(j + 1) & 31];
  float a2 = wx[2] * r[(j + 2) & 31];
  float a3 = uwf;
  #pragma unroll
  for (int i = 3; i < OBS; i += 3) {
    a0 += wx[i]     * r[(j + i)     & 31];
    a1 += wx[i + 1] * r[(j + i + 1) & 31];
    a2 += wx[i + 2] * r[(j + i + 2) & 31];
  }
  float out = (a0 + a1) + (a2 + a3);
  r[(j + 30) & 31] = out;   // becomes s_{t+1}[29]
  return out;
}

// C matrix via 30 unit-state chains; ran by lanes 0..31 of one extra block.
__device__ __forceinline__ void compute_C(const float* __restrict__ Wx) {
  int k = threadIdx.x;
  if (k >= 32) return;
  float wx[OBS];
  #pragma unroll
  for (int i = 0; i < OBS; ++i) wx[i] = Wx[i];
  float r[32];
  #pragma unroll
  for (int i = 0; i < 32; ++i) r[i] = (k < OBS && i == k) ? 1.f : 0.f;
  #pragma unroll 1
  for (int blk = 0; blk < LCH / 32; ++blk) {
    #pragma unroll
    for (int j = 0; j < 32; ++j)
      g_C[(blk * 32 + j) * 32 + k] = step_ring(r, wx, j, 0.f);
  }
}

// ---- pass A: zero-init chunk recurrence, writes PARTICULAR outputs to out ----
__global__ void __launch_bounds__(256) k_passA(const float* __restrict__ u,
                                               const float* __restrict__ Wx,
                                               const float* __restrict__ Wf,
                                               float* __restrict__ out) {
  if (blockIdx.x == NBLKA) {        // concurrent C-matrix block
    compute_C(Wx);
    return;
  }
  const int n = blockIdx.x * 256 + threadIdx.x;   // chain id
  const int b = n >> 5, c = n & (CCH - 1);
  float wx[OBS];
  #pragma unroll
  for (int i = 0; i < OBS; ++i) wx[i] = Wx[i];
  const float wf = Wf[0];
  float r[32];
  #pragma unroll
  for (int i = 0; i < 32; ++i) r[i] = 0.f;
  const float4* up = (const float4*)(u   + (size_t)b * NT + c * LCH);
  float4*       op = (float4*)      (out + (size_t)b * NT + c * LCH);
  #pragma unroll 1
  for (int blk = 0; blk < LCH / 32; ++blk) {
    #pragma unroll
    for (int q = 0; q < 8; ++q) {
      float4 u4 = up[blk * 8 + q];
      float4 o4;
      o4.x = step_ring(r, wx, q * 4 + 0, wf * u4.x);
      o4.y = step_ring(r, wx, q * 4 + 1, wf * u4.y);
      o4.z = step_ring(r, wx, q * 4 + 2, wf * u4.z);
      o4.w = step_ring(r, wx, q * 4 + 3, wf * u4.w);
      op[blk * 8 + q] = o4;
    }
  }
}

// ---- fused scan + correction: 8 batch rows per block, 32 lanes per row ----
// Per chunk c: load particular tile (its tail IS p_c), scan s_{c+1}=A^L s_c+p_c
// via shfl, add C[t]�s_c to the tile, store. No serial recompute, no g_s/g_p.
__global__ void __launch_bounds__(256) k_scancorr(const float* __restrict__ x0,
                                                  float* __restrict__ out) {
  __shared__ float Cl[LCH * 33];    // C padded: row t at Cl[t*33 + i]
  __shared__ float tile[8 * 65];    // 8 rows x 64 outputs, padded
  const int tid = threadIdx.x;
  const int b0  = blockIdx.x * 8;
  const int r   = tid >> 5;         // row within block (0..7)
  const int k   = tid & 31;         // lane within row group

  #pragma unroll
  for (int i = tid; i < LCH * 32; i += 256) {
    int t = i >> 5, j = i & 31;
    Cl[t * 33 + j] = g_C[i];
  }
  // A^L row k = C[34+k][:]  (k >= OBS rows are zero)
  float arow[32];
  #pragma unroll
  for (int j = 0; j < 32; ++j)
    arow[j] = (k < OBS) ? g_C[(34 + k) * 32 + j] : 0.f;
  float s = (k < OBS) ? x0[(size_t)(b0 + r) * OBS + k] : 0.f;
  __syncthreads();

  float* orow = out + (size_t)(b0 + r) * NT;
  #pragma unroll 1
  for (int c = 0; c < CCH; ++c) {
    // cooperative tile load (particular values): thread -> (row r, t=2k,2k+1)
    float2 tv = *(const float2*)(orow + c * LCH + 2 * k);
    tile[r * 65 + 2 * k]     = tv.x;
    tile[r * 65 + 2 * k + 1] = tv.y;
    __syncthreads();

    float p     = (k < OBS) ? tile[r * 65 + 34 + k] : 0.f;  // particular final
    float snext = p;
    float v0 = tile[r * 65 + k];        // output at local t = k
    float v1 = tile[r * 65 + 32 + k];   // output at local t = k+32
    #pragma unroll
    for (int i = 0; i < OBS; ++i) {
      float si = __shfl(s, i, 32);      // s_c[i] broadcast within row group
      snext += arow[i] * si;            // scan: s_{c+1} = A^L s_c + p_c
      v0    += Cl[k * 33 + i] * si;     // correction: += C[t]�s_c
      v1    += Cl[(k + 32) * 33 + i] * si;
    }
    orow[c * LCH + k]      = v0;
    orow[c * LCH + 32 + k] = v1;
    s = snext;
    __syncthreads();                    // tile reused next chunk
  }
}

extern "C" void kernel_launch(void* const* d_in, const int* in_sizes, int n_in,
                              void* d_out, int out_size, void* d_ws, size_t ws_size,
                              hipStream_t stream) {
  const float* u  = (const float*)d_in[0];
  const float* x0 = (const float*)d_in[1];
  const float* Wx = (const float*)d_in[2];
  const float* Wf = (const float*)d_in[3];
  float* out = (float*)d_out;

  hipLaunchKernelGGL(k_passA,    dim3(NBLKA + 1), dim3(256), 0, stream, u, Wx, Wf, out);
  hipLaunchKernelGGL(k_scancorr, dim3(NB / 8),    dim3(256), 0, stream, x0, out);
}